// Round 7
// baseline (1602.649 us; speedup 1.0000x reference)
//
#include <hip/hip_runtime.h>

#define RC       6144       // rows = cols = 6144
#define OCSTRIDE 18432      // IC_N*9 floats per oc slice
#define NB       256        // matvec grid (1 block/CU)
#define NT       512        // threads per matvec block (8 waves)
#define RPB      24         // rows per block
#define UNSCALE  1.52587890625e-05f   // 2^-16 cancels fp8 256x encode scale per iter

typedef float v2f __attribute__((ext_vector_type(2)));

__device__ __forceinline__ float wave_reduce(float x) {
#pragma unroll
    for (int off = 32; off > 0; off >>= 1) x += __shfl_down(x, off, 64);
    return x;
}

__device__ __forceinline__ float dot8(uint2 w, float4 ua, float4 ub) {
    v2f f01 = __builtin_amdgcn_cvt_pk_f32_fp8(w.x, false);
    v2f f23 = __builtin_amdgcn_cvt_pk_f32_fp8(w.x, true);
    v2f f45 = __builtin_amdgcn_cvt_pk_f32_fp8(w.y, false);
    v2f f67 = __builtin_amdgcn_cvt_pk_f32_fp8(w.y, true);
    return f01.x*ua.x + f01.y*ua.y + f23.x*ua.z + f23.y*ua.w
         + f45.x*ub.x + f45.y*ub.y + f67.x*ub.z + f67.y*ub.w;
}

// ---------------------------------------------------------------------------
// Wq[r][c] = fp8_e4m3(256 * conv[oc][ic][hh][ww]), r=oc*3+hh, c=ic*3+ww.
// (R3-proven) thread writes 8 consecutive fp8; wave reads are line-complete.
__global__ __launch_bounds__(256) void convert_q_kernel(
    const float* __restrict__ conv, unsigned char* __restrict__ Wq)
{
    const int t  = blockIdx.x * 256 + threadIdx.x;
    const int o8 = t * 8;
    const int r  = o8 / RC;
    const int c0 = o8 % RC;
    const int oc = r / 3, hh = r % 3;
    const float* base = conv + (size_t)oc * OCSTRIDE + hh * 3;
    float f[8];
#pragma unroll
    for (int e = 0; e < 8; ++e) {
        const int c  = c0 + e;
        const int ic = c / 3, ww = c - 3 * ic;
        f[e] = base[ic * 9 + ww] * 256.0f;
    }
    int lo = __builtin_amdgcn_cvt_pk_fp8_f32(f[0], f[1], 0, false);
    lo     = __builtin_amdgcn_cvt_pk_fp8_f32(f[2], f[3], lo, true);
    int hi = __builtin_amdgcn_cvt_pk_fp8_f32(f[4], f[5], 0, false);
    hi     = __builtin_amdgcn_cvt_pk_fp8_f32(f[6], f[7], hi, true);
    *reinterpret_cast<uint2*>(Wq + o8) = make_uint2((unsigned)lo, (unsigned)hi);
}

// ---------------------------------------------------------------------------
// v_out[r] = Wq[r,:].u (raw, no normalization). Also zeroes zero_buf's slice
// so the NEXT dispatch (ustep) can atomically accumulate into it.
// 256 blocks x 512 thr; block = 24 rows; wave = 3 full rows.
__global__ __launch_bounds__(NT) void vstep_q_kernel(
    const unsigned char* __restrict__ Wq, const float* __restrict__ u,
    float* __restrict__ v_out, float* __restrict__ zero_buf)
{
    __shared__ float u_lds[RC];
    const int tid = threadIdx.x, lane = tid & 63, wid = tid >> 6;
    const int b = blockIdx.x;

    if (tid < RPB) zero_buf[b * RPB + tid] = 0.f;

    const float4* u4  = reinterpret_cast<const float4*>(u);
    float4*       ul4 = reinterpret_cast<float4*>(u_lds);
#pragma unroll
    for (int k = 0; k < 3; ++k) ul4[tid + NT * k] = u4[tid + NT * k];
    __syncthreads();

    const int r0 = b * RPB + wid * 3;
    const unsigned char* wrow = Wq + (size_t)r0 * RC;
    float a0 = 0.f, a1 = 0.f, a2 = 0.f;
#pragma unroll
    for (int ch = 0; ch < 12; ++ch) {
        const int c = ch * 512 + lane * 8;
        const float4 ua = *reinterpret_cast<const float4*>(u_lds + c);
        const float4 ub = *reinterpret_cast<const float4*>(u_lds + c + 4);
        const uint2 wA = *reinterpret_cast<const uint2*>(wrow + c);
        const uint2 wB = *reinterpret_cast<const uint2*>(wrow + RC + c);
        const uint2 wC = *reinterpret_cast<const uint2*>(wrow + 2 * RC + c);
        a0 += dot8(wA, ua, ub);
        a1 += dot8(wB, ua, ub);
        a2 += dot8(wC, ua, ub);
    }
    a0 = wave_reduce(a0);
    a1 = wave_reduce(a1);
    a2 = wave_reduce(a2);
    if (lane == 0) {
        v_out[r0 + 0] = a0;
        v_out[r0 + 1] = a1;
        v_out[r0 + 2] = a2;
    }
}

// ---------------------------------------------------------------------------
// u_next[c] += sum_{24 rows of block} Wq[r][c] * (v[r]*2^-16), via atomicAdd.
// 256 blocks x 512 thr; thread owns 12 consecutive cols.
__global__ __launch_bounds__(NT) void ustep_q_kernel(
    const unsigned char* __restrict__ Wq, const float* __restrict__ v,
    float* __restrict__ u_next)
{
    __shared__ float v_l[RPB];
    const int tid = threadIdx.x;
    const int b = blockIdx.x;
    if (tid < RPB) v_l[tid] = v[b * RPB + tid] * UNSCALE;
    __syncthreads();

    const unsigned char* wp = Wq + (size_t)(b * RPB) * RC + tid * 12;
    float acc[12];
#pragma unroll
    for (int e = 0; e < 12; ++e) acc[e] = 0.f;
#pragma unroll 4
    for (int r = 0; r < RPB; ++r) {
        const unsigned w0 = *reinterpret_cast<const unsigned*>(wp);
        const unsigned w1 = *reinterpret_cast<const unsigned*>(wp + 4);
        const unsigned w2 = *reinterpret_cast<const unsigned*>(wp + 8);
        wp += RC;
        const float vv = v_l[r];
        const v2f a01 = __builtin_amdgcn_cvt_pk_f32_fp8(w0, false);
        const v2f a23 = __builtin_amdgcn_cvt_pk_f32_fp8(w0, true);
        const v2f b01 = __builtin_amdgcn_cvt_pk_f32_fp8(w1, false);
        const v2f b23 = __builtin_amdgcn_cvt_pk_f32_fp8(w1, true);
        const v2f c01 = __builtin_amdgcn_cvt_pk_f32_fp8(w2, false);
        const v2f c23 = __builtin_amdgcn_cvt_pk_f32_fp8(w2, true);
        acc[0]  += a01.x * vv; acc[1]  += a01.y * vv;
        acc[2]  += a23.x * vv; acc[3]  += a23.y * vv;
        acc[4]  += b01.x * vv; acc[5]  += b01.y * vv;
        acc[6]  += b23.x * vv; acc[7]  += b23.y * vv;
        acc[8]  += c01.x * vv; acc[9]  += c01.y * vv;
        acc[10] += c23.x * vv; acc[11] += c23.y * vv;
    }
    float* up = u_next + tid * 12;
#pragma unroll
    for (int j = 0; j < 12; ++j) atomicAdd(&up[j], acc[j]);
}

// ---------------------------------------------------------------------------
// out = (3/256) * dot(v,t) / (|v| |u|)   — fp8 sigma (R6-validated, absmax 0)
__global__ __launch_bounds__(NT) void final_kernel(
    const float* __restrict__ v, const float* __restrict__ t,
    const float* __restrict__ u, float* __restrict__ out)
{
    __shared__ float sv[8], sd[8], su[8];
    const int tid = threadIdx.x, lane = tid & 63, wid = tid >> 6;
    float vs = 0.f, dot = 0.f, us = 0.f;
#pragma unroll
    for (int k = 0; k < 12; ++k) {
        const float x = v[tid + NT * k];
        const float y = t[tid + NT * k];
        const float z = u[tid + NT * k];
        vs += x * x; dot += x * y; us += z * z;
    }
    vs  = wave_reduce(vs);
    dot = wave_reduce(dot);
    us  = wave_reduce(us);
    if (lane == 0) { sv[wid] = vs; sd[wid] = dot; su[wid] = us; }
    __syncthreads();
    if (tid == 0) {
        float tvs = 0.f, tdot = 0.f, tus = 0.f;
#pragma unroll
        for (int w = 0; w < 8; ++w) { tvs += sv[w]; tdot += sd[w]; tus += su[w]; }
        out[0] = 0.01171875f * tdot * rsqrtf(tvs) * rsqrtf(tus);   // 3/256
    }
}

extern "C" void kernel_launch(void* const* d_in, const int* in_sizes, int n_in,
                              void* d_out, int out_size, void* d_ws, size_t ws_size,
                              hipStream_t stream)
{
    const float* conv = (const float*)d_in[0];   // [2048,2048,3,3] fp32
    const float* u_in = (const float*)d_in[1];   // [1,6144] fp32, unit norm
    float* out = (float*)d_out;

    // ws layout (bytes): Wq[37748736] | ub0[24576] | ub1[24576] | v[24576] | t[24576]
    const size_t WQ_BYTES = (size_t)RC * RC;
    const size_t VECB     = (size_t)RC * sizeof(float);
    const size_t needed   = WQ_BYTES + 4 * VECB;
    if (ws_size < needed) return;

    unsigned char* Wq = (unsigned char*)d_ws;
    float* ub0   = (float*)((char*)d_ws + WQ_BYTES);
    float* ub1   = ub0 + RC;
    float* v_vec = ub1 + RC;
    float* t_vec = v_vec + RC;
    float* ub[2] = {ub0, ub1};

    convert_q_kernel<<<RC * RC / 8 / 256, 256, 0, stream>>>(conv, Wq);

    for (int i = 0; i < 10; ++i) {
        const float* usrc = (i == 0) ? u_in : ub[(i + 1) & 1];
        float*       unxt = ub[i & 1];
        // vstep zeroes unxt (consumed by NEXT dispatch's atomics — ordered by stream)
        vstep_q_kernel<<<NB, NT, 0, stream>>>(Wq, usrc, v_vec, unxt);
        ustep_q_kernel<<<NB, NT, 0, stream>>>(Wq, v_vec, unxt);
    }
    // u10 = ub1 (i=9 wrote ub[1]); v_vec = v10 = Wq*u9. t = Wq*u10 (zeroes dead ub0).
    vstep_q_kernel<<<NB, NT, 0, stream>>>(Wq, ub1, t_vec, ub0);
    final_kernel<<<1, NT, 0, stream>>>(v_vec, t_vec, ub1, out);
}